// Round 14
// baseline (66.111 us; speedup 1.0000x reference)
//
#include <hip/hip_runtime.h>

typedef float v4f   __attribute__((ext_vector_type(4)));
typedef float f32x4 __attribute__((ext_vector_type(4)));
typedef _Float16 h4 __attribute__((ext_vector_type(4)));
typedef _Float16 h8 __attribute__((ext_vector_type(8)));

#define HH 512
#define WW 512
#define NPLANES 96
#define NSTRIP 32
#define NBLK (NPLANES * NSTRIP)   // 3072
#define C1V 1e-4f
#define C2V 9e-4f
#define EPSV 1e-8f
#define NPIX 25165824.0f          // 32*3*512*512

// LDS H-ring: [q 5][slot 5][col 16][48 B + pad]; slots 0..3 ring, slot 4 = zeros.
// SLOT_B = 784 (768 data + 16 pad): slot step = 196 dwords = +4 banks/slot ->
// different ring slots no longer collide on the same banks (was 4-way at 768).
#define SLOT_B 784
#define Q_B    3920               // 5 slots
#define LDS_B  19600

#define MF(A, B) __builtin_amdgcn_mfma_f32_16x16x32_f16((A), (B), zf, 0, 0, 0)

// 11-way select from named weight scalars (no arrays -> no scratch)
#define SELW(DST, IX) { const int ix_ = (IX); float r_ = 0.f; \
  r_ = (ix_ == 0) ? wv0 : r_;  r_ = (ix_ == 1) ? wv1 : r_; \
  r_ = (ix_ == 2) ? wv2 : r_;  r_ = (ix_ == 3) ? wv3 : r_; \
  r_ = (ix_ == 4) ? wv4 : r_;  r_ = (ix_ == 5) ? wv5 : r_; \
  r_ = (ix_ == 6) ? wv6 : r_;  r_ = (ix_ == 7) ? wv7 : r_; \
  r_ = (ix_ == 8) ? wv8 : r_;  r_ = (ix_ == 9) ? wv9 : r_; \
  r_ = (ix_ == 10) ? wv10 : r_; DST = r_; }

// f32 -> f16 pack via RNE casts (v_cvt_f16_f32), unbiased
#define PACK8(DST, F0,F1,F2,F3,F4,F5,F6,F7) \
  DST = (h8){(_Float16)(F0),(_Float16)(F1),(_Float16)(F2),(_Float16)(F3), \
             (_Float16)(F4),(_Float16)(F5),(_Float16)(F6),(_Float16)(F7)};

#define EPX(M) { \
  const float mux_ = mx[M], muy_ = my[M]; \
  const float mx2_ = mux_ * mux_, my2_ = muy_ * muy_, mxy_ = mux_ * muy_; \
  const float sx2_ = vx2[M] - mx2_, sy2_ = vy2[M] - my2_, sxy_ = vxy[M] - mxy_; \
  const float num_ = fmaf(2.f, mxy_, C1V) * fmaf(2.f, sxy_, C2V); \
  const float den_ = (mx2_ + my2_ + C1V) * (sx2_ + sy2_ + C2V) + EPSV; \
  acc = fmaf(num_, __builtin_amdgcn_rcpf(den_), acc); }

// V operand fetch for out-chunk TAU (issued EARLY; consumed by VMFMA late).
// Lane (n,s) reads 8 rows of col n from H chunk ch_ (zero slot outside image).
#define VLOAD(TAU) { \
  const int tau_ = (TAU); \
  const int ch_ = tau_ - 1 + ((s + 1) >> 1); \
  const int slot_ = ((unsigned)ch_ < 32u) ? (ch_ & 3) : 4; \
  const char* rb_ = lds + slot_ * SLOT_B + rByte; \
  vbx  = *(const h8*)(rb_); \
  vby  = *(const h8*)(rb_ + Q_B); \
  vbx2 = *(const h8*)(rb_ + 2 * Q_B); \
  vby2 = *(const h8*)(rb_ + 3 * Q_B); \
  vbxy = *(const h8*)(rb_ + 4 * Q_B); }

#define VMFMA { \
  const f32x4 mx  = MF(Wf, vbx);  const f32x4 my  = MF(Wf, vby); \
  const f32x4 vx2 = MF(Wf, vbx2); const f32x4 vy2 = MF(Wf, vby2); \
  const f32x4 vxy = MF(Wf, vbxy); \
  EPX(0) EPX(1) EPX(2) EPX(3) }

// step T: [issue V-reads for chunk T-2] -> [prefetch raw chunk T+1] ->
// [H: pack/square/5 MFMA of chunk T] -> [H-writes slot T&3] -> [V MFMA+EPX].
// V lags H by 2 chunks so every LDS slot read was written >= 1 step ago
// (kills the zero-distance ds_write->ds_read stall of R13).
#define STEP(T, CXA,CXB,CYA,CYB, NXA,NXB,NYA,NYB) { \
  const int t_ = (T); \
  if (t_ >= 2) VLOAD(t_ - 2) \
  if (t_ < 31) { \
    NXA = *(const v4f*)pXa; NXB = *(const v4f*)pXb; \
    NYA = *(const v4f*)pYa; NYB = *(const v4f*)pYb; \
    pXa += 16 * WW; pXb += 16 * WW; pYa += 16 * WW; pYb += 16 * WW; \
  } \
  h8 ax, ay; \
  PACK8(ax, CXA[0],CXA[1],CXA[2],CXA[3], CXB[0],CXB[1],CXB[2],CXB[3]) \
  PACK8(ay, CYA[0],CYA[1],CYA[2],CYA[3], CYB[0],CYB[1],CYB[2],CYB[3]) \
  const h8 ax2 = ax * ax, ay2 = ay * ay, axy = ax * ay; \
  const f32x4 chx  = MF(ax,  WfH); const f32x4 chy  = MF(ay,  WfH); \
  const f32x4 chx2 = MF(ax2, WfH); const f32x4 chy2 = MF(ay2, WfH); \
  const f32x4 chxy = MF(axy, WfH); \
  { char* wb_ = lds + (t_ & 3) * SLOT_B + wByte; \
    *(h4*)(wb_)         = (h4){(_Float16)chx[0], (_Float16)chx[1], (_Float16)chx[2], (_Float16)chx[3]}; \
    *(h4*)(wb_ + Q_B)   = (h4){(_Float16)chy[0], (_Float16)chy[1], (_Float16)chy[2], (_Float16)chy[3]}; \
    *(h4*)(wb_ + 2*Q_B) = (h4){(_Float16)chx2[0],(_Float16)chx2[1],(_Float16)chx2[2],(_Float16)chx2[3]}; \
    *(h4*)(wb_ + 3*Q_B) = (h4){(_Float16)chy2[0],(_Float16)chy2[1],(_Float16)chy2[2],(_Float16)chy2[3]}; \
    *(h4*)(wb_ + 4*Q_B) = (h4){(_Float16)chxy[0],(_Float16)chxy[1],(_Float16)chxy[2],(_Float16)chxy[3]}; } \
  if (t_ >= 2) VMFMA }

__global__ __launch_bounds__(64)
void ssim_main(const float* __restrict__ x, const float* __restrict__ y,
               float* __restrict__ partial)
{
  __shared__ __attribute__((aligned(16))) char lds[LDS_B];

  const int l = threadIdx.x;
  const int n = l & 15;     // H: A-row (image row in chunk); V: B/D col (out col)
  const int s = l >> 4;     // k quadrant (8 consecutive k)

  // XCD swizzle: each XCD gets 384 consecutive (plane,strip) units -> halo L2 reuse
  const int wg = blockIdx.x;
  const int swz = (wg & 7) * (NBLK / 8) + (wg >> 3);
  const int plane = swz >> 5;
  const int strip = swz & 31;
  const int C0 = strip * 16;

  const float* xp = x + (size_t)plane * (HH * WW);
  const float* yp = y + (size_t)plane * (HH * WW);

  // Gaussian window (exact reference formula), named scalars -> SGPRs
  float wv0, wv1, wv2, wv3, wv4, wv5, wv6, wv7, wv8, wv9, wv10;
#define WINIT(k) wv##k = expf(-((float)((k - 5) * (k - 5))) / 4.5f);
  WINIT(0) WINIT(1) WINIT(2) WINIT(3) WINIT(4) WINIT(5)
  WINIT(6) WINIT(7) WINIT(8) WINIT(9) WINIT(10)
#undef WINIT
  const float inv_ = 1.f / (wv0 + wv1 + wv2 + wv3 + wv4 + wv5 + wv6 + wv7 + wv8 + wv9 + wv10);
#define WNORM(k) wv##k = __int_as_float(__builtin_amdgcn_readfirstlane(__float_as_int(wv##k * inv_)));
  WNORM(0) WNORM(1) WNORM(2) WNORM(3) WNORM(4) WNORM(5)
  WNORM(6) WNORM(7) WNORM(8) WNORM(9) WNORM(10)
#undef WNORM

  const f32x4 zf = {0.f, 0.f, 0.f, 0.f};

  // shared banded weight fragment: W[k][i] = w[k-i-3], i = l&15, k = 8s+j.
  // Used as B in H (i=out-col) and as A in V (i=out-row) -- same registers.
  h8 Wf;
  {
    const int kb = 8 * s;
    float b0,b1,b2,b3,b4,b5,b6,b7;
    SELW(b0, kb + 0 - n - 3) SELW(b1, kb + 1 - n - 3)
    SELW(b2, kb + 2 - n - 3) SELW(b3, kb + 3 - n - 3)
    SELW(b4, kb + 4 - n - 3) SELW(b5, kb + 5 - n - 3)
    SELW(b6, kb + 6 - n - 3) SELW(b7, kb + 7 - n - 3)
    PACK8(Wf, b0,b1,b2,b3,b4,b5,b6,b7)
  }

  // H raw-tap window: cols C0-8+8s .. +7. Kill whole group if fully outside
  // (strip 0/s=0, strip 31/s=3): zero H weights; loads read clamped valid mem.
  const int cb = C0 - 8 + 8 * s;
  const bool kill = (cb < 0) || (cb >= WW);
  h8 WfH = Wf;
  if (kill) WfH = (h8)(_Float16)0.f;
  const int ca = kill ? 0 : cb;

  const float* pXa = xp + n * WW + ca;
  const float* pXb = pXa + 4;
  const float* pYa = yp + n * WW + ca;
  const float* pYb = pYa + 4;

  const int wByte = n * 48 + 8 * s;                    // store: col n, rows 4s..4s+3
  const int rByte = n * 48 + 16 * ((s + 1) & 1);       // read: col n, rowbase {8,0,8,0}

  // zero-slot init (slot 4, all 5 quantities; data region = 768 B per q)
  #pragma unroll
  for (int q = 0; q < 5; ++q)
    #pragma unroll
    for (int j = 0; j < 3; ++j)
      *(unsigned*)(lds + q * Q_B + 4 * SLOT_B + 4 * (l + 64 * j)) = 0u;

  // V operand registers (filled by VLOAD, consumed by VMFMA)
  h8 vbx, vby, vbx2, vby2, vbxy;
  float acc = 0.f;

  // prologue: chunk 0 into A-set
  v4f XA0 = *(const v4f*)pXa, XB0 = *(const v4f*)pXb;
  v4f YA0 = *(const v4f*)pYa, YB0 = *(const v4f*)pYb;
  pXa += 16 * WW; pXb += 16 * WW; pYa += 16 * WW; pYb += 16 * WW;
  v4f XA1, XB1, YA1, YB1;

  #pragma unroll 1
  for (int u = 0; u < 16; ++u) {
    STEP(2 * u,     XA0, XB0, YA0, YB0,  XA1, XB1, YA1, YB1)
    STEP(2 * u + 1, XA1, XB1, YA1, YB1,  XA0, XB0, YA0, YB0)
  }
  // tail: out-chunks 30 and 31 (chunk 32 -> zero slot)
  VLOAD(30) VMFMA
  VLOAD(31) VMFMA

  // wave reduction -> per-block partial
  #pragma unroll
  for (int off = 32; off > 0; off >>= 1) acc += __shfl_down(acc, off);
  if (l == 0) partial[wg] = acc;
}

__global__ void finalize_kernel(const float* __restrict__ partial, float* __restrict__ out)
{
  __shared__ float s4[4];
  float a = 0.f;
  for (int i = threadIdx.x; i < NBLK; i += 256) a += partial[i];
  #pragma unroll
  for (int off = 32; off > 0; off >>= 1) a += __shfl_down(a, off);
  if ((threadIdx.x & 63) == 0) s4[threadIdx.x >> 6] = a;
  __syncthreads();
  if (threadIdx.x == 0) out[0] = 1.f - (s4[0] + s4[1] + s4[2] + s4[3]) * (1.f / NPIX);
}

extern "C" void kernel_launch(void* const* d_in, const int* in_sizes, int n_in,
                              void* d_out, int out_size, void* d_ws, size_t ws_size,
                              hipStream_t stream)
{
  const float* x = (const float*)d_in[0];
  const float* y = (const float*)d_in[1];
  float* ws = (float*)d_ws;
  float* out = (float*)d_out;

  hipLaunchKernelGGL(ssim_main, dim3(NBLK), dim3(64), 0, stream, x, y, ws);
  hipLaunchKernelGGL(finalize_kernel, dim3(1), dim3(256), 0, stream, ws, out);
}